// Round 1
// baseline (685.518 us; speedup 1.0000x reference)
//
#include <hip/hip_runtime.h>
#include <hip/hip_bf16.h>

// Problem constants (B=2, T=512, H=1024, V=50000)
#define M_DIM 1024      // B*T rows
#define K_DIM 1024      // H
#define V_DIM 50000     // vocab (N)
#define NPAD  50048     // V padded to multiple of 128

typedef __attribute__((ext_vector_type(8))) short short8;
typedef __attribute__((ext_vector_type(4))) float floatx4;

__device__ inline unsigned short f32_to_bf16(float f) {
    unsigned int u = __float_as_uint(f);
    u += 0x7FFF + ((u >> 16) & 1);   // round-to-nearest-even
    return (unsigned short)(u >> 16);
}

// async global->LDS, 16 bytes per lane (global_load_lds_dwordx4)
__device__ inline void async_copy16(const unsigned short* g, unsigned short* l) {
    __builtin_amdgcn_global_load_lds(
        (const __attribute__((address_space(1))) unsigned int*)g,
        (__attribute__((address_space(3))) unsigned int*)l,
        16, 0, 0);
}

// fp32 -> bf16 (8 elems/thread); pads [n_valid, n_total) with zeros
__global__ __launch_bounds__(256) void convert_bf16_kernel(
    const float* __restrict__ src, unsigned short* __restrict__ dst,
    size_t n_valid, size_t n_total)
{
    size_t i = ((size_t)blockIdx.x * 256 + threadIdx.x) * 8;
    if (i >= n_total) return;
    unsigned short h[8];
    if (i < n_valid) {
        const float4* p = (const float4*)(src + i);
        float4 a = p[0], b = p[1];
        h[0] = f32_to_bf16(a.x); h[1] = f32_to_bf16(a.y);
        h[2] = f32_to_bf16(a.z); h[3] = f32_to_bf16(a.w);
        h[4] = f32_to_bf16(b.x); h[5] = f32_to_bf16(b.y);
        h[6] = f32_to_bf16(b.z); h[7] = f32_to_bf16(b.w);
    } else {
        #pragma unroll
        for (int j = 0; j < 8; ++j) h[j] = 0;
    }
    uint4 o;
    o.x = (unsigned)h[0] | ((unsigned)h[1] << 16);
    o.y = (unsigned)h[2] | ((unsigned)h[3] << 16);
    o.z = (unsigned)h[4] | ((unsigned)h[5] << 16);
    o.w = (unsigned)h[6] | ((unsigned)h[7] << 16);
    *(uint4*)(dst + i) = o;
}

// 128x128 tile GEMM (A[M,K] x W[N,K]^T), BK=32, 4 waves (2x2), each wave 64x64.
// Epilogue stores logits and accumulates BCE-with-logits loss terms.
__global__ __launch_bounds__(256) void gemm_loss_kernel(
    const unsigned short* __restrict__ Ab,    // [M_DIM][K_DIM] bf16
    const unsigned short* __restrict__ Wb,    // [NPAD][K_DIM] bf16 (zero-padded)
    const int*            __restrict__ labels,// [M_DIM]
    const float*          __restrict__ amask, // [M_DIM]
    float*                __restrict__ out,   // logits [M_DIM][V_DIM]
    double*               __restrict__ loss_acc)
{
    __shared__ unsigned short As[128 * 32];   // 8 KB
    __shared__ unsigned short Bs[128 * 32];   // 8 KB
    __shared__ float red[256];

    const int tid  = threadIdx.x;
    const int lane = tid & 63;
    const int wave = tid >> 6;
    const int wm   = (wave >> 1) * 64;        // wave row offset in 128-tile
    const int wn   = (wave & 1) * 64;         // wave col offset
    const int bm   = blockIdx.x;              // 0..7
    const int bn   = blockIdx.y;              // 0..390

    floatx4 acc[4][4] = {};

    // staging: tile = 128 rows x 32 bf16 = 512 chunks of 16B; thread t owns chunks t, t+256
    const int c0 = tid, c1 = tid + 256;
    const unsigned short* gA0 = Ab + (size_t)(bm * 128 + (c0 >> 2)) * K_DIM + (c0 & 3) * 8;
    const unsigned short* gA1 = Ab + (size_t)(bm * 128 + (c1 >> 2)) * K_DIM + (c1 & 3) * 8;
    const unsigned short* gB0 = Wb + (size_t)(bn * 128 + (c0 >> 2)) * K_DIM + (c0 & 3) * 8;
    const unsigned short* gB1 = Wb + (size_t)(bn * 128 + (c1 >> 2)) * K_DIM + (c1 & 3) * 8;
    unsigned short* lA0 = &As[c0 * 8];
    unsigned short* lA1 = &As[c1 * 8];
    unsigned short* lB0 = &Bs[c0 * 8];
    unsigned short* lB1 = &Bs[c1 * 8];

    const int frow = lane & 15;               // fragment row/col within 16
    const int fk   = (lane >> 4) * 8;         // fragment k offset

    for (int k0 = 0; k0 < K_DIM; k0 += 32) {
        async_copy16(gA0 + k0, lA0);
        async_copy16(gA1 + k0, lA1);
        async_copy16(gB0 + k0, lB0);
        async_copy16(gB1 + k0, lB1);
        __syncthreads();   // compiler drains vmcnt before s_barrier

        short8 af[4], bfr[4];
        #pragma unroll
        for (int i = 0; i < 4; ++i) {
            af[i]  = *(const short8*)&As[(wm + i * 16 + frow) * 32 + fk];
            bfr[i] = *(const short8*)&Bs[(wn + i * 16 + frow) * 32 + fk];
        }
        #pragma unroll
        for (int mi = 0; mi < 4; ++mi)
            #pragma unroll
            for (int ni = 0; ni < 4; ++ni)
                acc[mi][ni] = __builtin_amdgcn_mfma_f32_16x16x32_bf16(
                    af[mi], bfr[ni], acc[mi][ni], 0, 0, 0);
        __syncthreads();
    }

    // Epilogue: C/D layout col=lane&15, row=(lane>>4)*4 + r
    float lsum = 0.0f;
    const int row0 = bm * 128 + wm;
    const int col0 = bn * 128 + wn;
    #pragma unroll
    for (int mi = 0; mi < 4; ++mi) {
        #pragma unroll
        for (int r = 0; r < 4; ++r) {
            const int grow = row0 + mi * 16 + (lane >> 4) * 4 + r;
            const int lab  = labels[grow];
            const float m  = amask[grow];
            #pragma unroll
            for (int ni = 0; ni < 4; ++ni) {
                const int gcol = col0 + ni * 16 + (lane & 15);
                const float x = acc[mi][ni][r];
                if (gcol < V_DIM) {
                    out[(size_t)grow * V_DIM + gcol] = x;
                    float base = fmaxf(x, 0.0f) + log1pf(__expf(-fabsf(x)));
                    float c = base;
                    if (lab == gcol && m > 0.0f) c -= x;  // gathered term (valid => lab>=0)
                    lsum += c * m;
                }
            }
        }
    }

    red[tid] = lsum;
    __syncthreads();
    #pragma unroll
    for (int s = 128; s > 0; s >>= 1) {
        if (tid < s) red[tid] += red[tid + s];
        __syncthreads();
    }
    if (tid == 0) atomicAdd(loss_acc, (double)red[0]);
}

__global__ __launch_bounds__(256) void finalize_kernel(
    const float* __restrict__ amask, const double* __restrict__ loss_acc,
    float* __restrict__ out_loss)
{
    __shared__ float red[256];
    float s = 0.0f;
    for (int i = threadIdx.x; i < M_DIM; i += 256) s += amask[i];
    red[threadIdx.x] = s;
    __syncthreads();
    for (int k = 128; k > 0; k >>= 1) {
        if (threadIdx.x < k) red[threadIdx.x] += red[threadIdx.x + k];
        __syncthreads();
    }
    if (threadIdx.x == 0)
        *out_loss = (float)(*loss_acc / (double)red[0]);
}

extern "C" void kernel_launch(void* const* d_in, const int* in_sizes, int n_in,
                              void* d_out, int out_size, void* d_ws, size_t ws_size,
                              hipStream_t stream) {
    const float* hidden = (const float*)d_in[0];  // [2,512,1024] fp32
    const float* W      = (const float*)d_in[1];  // [50000,1024] fp32
    const int*   labels = (const int*)d_in[2];    // [2,512] int
    const float* amask  = (const float*)d_in[3];  // [2,512] fp32
    float* out = (float*)d_out;                   // 51,200,000 logits + 1 loss

    // workspace layout: Wb (bf16, padded) | Ab (bf16) | loss accumulator (double)
    unsigned short* Wb = (unsigned short*)d_ws;
    unsigned short* Ab = Wb + (size_t)NPAD * K_DIM;
    double* loss_acc   = (double*)(Ab + (size_t)M_DIM * K_DIM);

    hipMemsetAsync(loss_acc, 0, sizeof(double), stream);

    // convert W: 50048*1024 total elems / 8 per thread / 256 per block = 25024 blocks
    convert_bf16_kernel<<<25024, 256, 0, stream>>>(
        W, Wb, (size_t)V_DIM * K_DIM, (size_t)NPAD * K_DIM);
    // convert hidden: 1048576 / 8 / 256 = 512 blocks
    convert_bf16_kernel<<<512, 256, 0, stream>>>(
        hidden, Ab, (size_t)M_DIM * K_DIM, (size_t)M_DIM * K_DIM);

    dim3 grid(M_DIM / 128, NPAD / 128);  // (8, 391)
    gemm_loss_kernel<<<grid, 256, 0, stream>>>(Ab, Wb, labels, amask, out, loss_acc);

    finalize_kernel<<<1, 256, 0, stream>>>(amask, loss_acc, out + (size_t)M_DIM * V_DIM);
}

// Round 2
// 570.113 us; speedup vs baseline: 1.2024x; 1.2024x over previous
//
#include <hip/hip_runtime.h>
#include <hip/hip_bf16.h>

// Problem constants (B=2, T=512, H=1024, V=50000)
#define M_DIM 1024      // B*T rows
#define K_DIM 1024      // H
#define V_DIM 50000     // vocab (N)
#define NPAD  50048     // V padded to multiple of 128
#define NBLK  (NPAD / 128)       // 391
#define WCONV_BLOCKS 25024       // NPAD*K_DIM/8/256
#define ACONV_BLOCKS 512         // M_DIM*K_DIM/8/256

typedef __attribute__((ext_vector_type(8))) short short8;
typedef __attribute__((ext_vector_type(4))) float floatx4;

__device__ inline unsigned short f32_to_bf16(float f) {
    unsigned int u = __float_as_uint(f);
    u += 0x7FFF + ((u >> 16) & 1);   // round-to-nearest-even
    return (unsigned short)(u >> 16);
}

// async global->LDS, 16 bytes per lane (global_load_lds_dwordx4)
__device__ inline void async_copy16(const unsigned short* g, unsigned short* l) {
    __builtin_amdgcn_global_load_lds(
        (const __attribute__((address_space(1))) unsigned int*)g,
        (__attribute__((address_space(3))) unsigned int*)l,
        16, 0, 0);
}

// One launch converting both W and hidden fp32 -> bf16 (8 elems/thread).
// W region zero-pads rows [V_DIM, NPAD).
__global__ __launch_bounds__(256) void convert_all_kernel(
    const float* __restrict__ W, const float* __restrict__ hidden,
    unsigned short* __restrict__ Wb, unsigned short* __restrict__ Ab)
{
    const float* src;
    unsigned short* dst;
    size_t n_valid, i;
    if (blockIdx.x < WCONV_BLOCKS) {
        src = W; dst = Wb; n_valid = (size_t)V_DIM * K_DIM;
        i = ((size_t)blockIdx.x * 256 + threadIdx.x) * 8;
    } else {
        src = hidden; dst = Ab; n_valid = (size_t)M_DIM * K_DIM;
        i = ((size_t)(blockIdx.x - WCONV_BLOCKS) * 256 + threadIdx.x) * 8;
    }
    unsigned short h[8];
    if (i < n_valid) {
        const float4* p = (const float4*)(src + i);
        float4 a = p[0], b = p[1];
        h[0] = f32_to_bf16(a.x); h[1] = f32_to_bf16(a.y);
        h[2] = f32_to_bf16(a.z); h[3] = f32_to_bf16(a.w);
        h[4] = f32_to_bf16(b.x); h[5] = f32_to_bf16(b.y);
        h[6] = f32_to_bf16(b.z); h[7] = f32_to_bf16(b.w);
    } else {
        #pragma unroll
        for (int j = 0; j < 8; ++j) h[j] = 0;
    }
    uint4 o;
    o.x = (unsigned)h[0] | ((unsigned)h[1] << 16);
    o.y = (unsigned)h[2] | ((unsigned)h[3] << 16);
    o.z = (unsigned)h[4] | ((unsigned)h[5] << 16);
    o.w = (unsigned)h[6] | ((unsigned)h[7] << 16);
    *(uint4*)(dst + i) = o;
}

// fast softplus(-|x|): log(1+exp(-|x|)) via hw exp/log; abs err ~1e-7,
// loss threshold is ~742 -> plenty of margin.
__device__ __forceinline__ float bce_base(float x) {
    return fmaxf(x, 0.0f) + __logf(1.0f + __expf(-fabsf(x)));
}

template<bool CHECK>
__device__ __forceinline__ float epilogue_store(
    const floatx4 acc[4][4], float* __restrict__ out,
    const int* __restrict__ lab_s, const float* __restrict__ msk_s,
    int bm, int wm, int col0, int lane)
{
    float lsum = 0.0f;
    #pragma unroll
    for (int mi = 0; mi < 4; ++mi) {
        #pragma unroll
        for (int r = 0; r < 4; ++r) {
            const int trow = wm + mi * 16 + (lane >> 4) * 4 + r;  // 0..127 in tile
            const int lab  = lab_s[trow];
            const float m  = msk_s[trow];
            float* orow = out + (size_t)(bm * 128 + trow) * V_DIM;
            #pragma unroll
            for (int ni = 0; ni < 4; ++ni) {
                const int gcol = col0 + ni * 16 + (lane & 15);
                const float x = acc[mi][ni][r];
                if (!CHECK || gcol < V_DIM) {
                    orow[gcol] = x;
                    float c = bce_base(x);
                    if (lab == gcol) c -= x;   // mask==0 rows contribute 0 via *m
                    lsum += c * m;
                }
            }
        }
    }
    return lsum;
}

// 128x128 tile GEMM (A[M,K] x W[N,K]^T), BK=32, 4 waves (2x2), each wave 64x64.
// Epilogue stores logits and accumulates BCE-with-logits loss terms.
__global__ __launch_bounds__(256) void gemm_loss_kernel(
    const unsigned short* __restrict__ Ab,    // [M_DIM][K_DIM] bf16
    const unsigned short* __restrict__ Wb,    // [NPAD][K_DIM] bf16 (zero-padded)
    const int*            __restrict__ labels,// [M_DIM]
    const float*          __restrict__ amask, // [M_DIM]
    float*                __restrict__ out,   // logits [M_DIM][V_DIM]
    double*               __restrict__ loss_acc)
{
    __shared__ unsigned short As[128 * 32];   // 8 KB
    __shared__ unsigned short Bs[128 * 32];   // 8 KB
    __shared__ int   lab_s[128];
    __shared__ float msk_s[128];
    __shared__ float wred[4];

    const int tid  = threadIdx.x;
    const int lane = tid & 63;
    const int wave = tid >> 6;
    const int wm   = (wave >> 1) * 64;        // wave row offset in 128-tile
    const int wn   = (wave & 1) * 64;         // wave col offset
    const int bm   = blockIdx.x;              // 0..7
    const int bn   = blockIdx.y;              // 0..390

    if (tid < 128) {
        lab_s[tid] = labels[bm * 128 + tid];
        msk_s[tid] = amask[bm * 128 + tid];
    }

    floatx4 acc[4][4] = {};

    // staging: tile = 128 rows x 32 bf16 = 512 chunks of 16B; thread t owns chunks t, t+256
    const int c0 = tid, c1 = tid + 256;
    const unsigned short* gA0 = Ab + (size_t)(bm * 128 + (c0 >> 2)) * K_DIM + (c0 & 3) * 8;
    const unsigned short* gA1 = Ab + (size_t)(bm * 128 + (c1 >> 2)) * K_DIM + (c1 & 3) * 8;
    const unsigned short* gB0 = Wb + (size_t)(bn * 128 + (c0 >> 2)) * K_DIM + (c0 & 3) * 8;
    const unsigned short* gB1 = Wb + (size_t)(bn * 128 + (c1 >> 2)) * K_DIM + (c1 & 3) * 8;
    unsigned short* lA0 = &As[c0 * 8];
    unsigned short* lA1 = &As[c1 * 8];
    unsigned short* lB0 = &Bs[c0 * 8];
    unsigned short* lB1 = &Bs[c1 * 8];

    const int frow = lane & 15;               // fragment row/col within 16
    const int fk   = (lane >> 4) * 8;         // fragment k offset

    for (int k0 = 0; k0 < K_DIM; k0 += 32) {
        async_copy16(gA0 + k0, lA0);
        async_copy16(gA1 + k0, lA1);
        async_copy16(gB0 + k0, lB0);
        async_copy16(gB1 + k0, lB1);
        __syncthreads();   // compiler drains vmcnt before s_barrier

        short8 af[4], bfr[4];
        #pragma unroll
        for (int i = 0; i < 4; ++i) {
            af[i]  = *(const short8*)&As[(wm + i * 16 + frow) * 32 + fk];
            bfr[i] = *(const short8*)&Bs[(wn + i * 16 + frow) * 32 + fk];
        }
        #pragma unroll
        for (int mi = 0; mi < 4; ++mi)
            #pragma unroll
            for (int ni = 0; ni < 4; ++ni)
                acc[mi][ni] = __builtin_amdgcn_mfma_f32_16x16x32_bf16(
                    af[mi], bfr[ni], acc[mi][ni], 0, 0, 0);
        __syncthreads();
    }

    // Epilogue: C/D layout col=lane&15, row=(lane>>4)*4 + r
    const int col0 = bn * 128 + wn;
    float lsum;
    if (bn < NBLK - 1) {
        lsum = epilogue_store<false>(acc, out, lab_s, msk_s, bm, wm, col0, lane);
    } else {
        lsum = epilogue_store<true>(acc, out, lab_s, msk_s, bm, wm, col0, lane);
    }

    // wave shuffle reduce, then one atomic per block
    #pragma unroll
    for (int off = 32; off > 0; off >>= 1) lsum += __shfl_down(lsum, off);
    if (lane == 0) wred[wave] = lsum;
    __syncthreads();
    if (tid == 0)
        atomicAdd(loss_acc, (double)(wred[0] + wred[1] + wred[2] + wred[3]));
}

__global__ __launch_bounds__(256) void finalize_kernel(
    const float* __restrict__ amask, const double* __restrict__ loss_acc,
    float* __restrict__ out_loss)
{
    __shared__ float red[256];
    float s = 0.0f;
    for (int i = threadIdx.x; i < M_DIM; i += 256) s += amask[i];
    red[threadIdx.x] = s;
    __syncthreads();
    for (int k = 128; k > 0; k >>= 1) {
        if (threadIdx.x < k) red[threadIdx.x] += red[threadIdx.x + k];
        __syncthreads();
    }
    if (threadIdx.x == 0)
        *out_loss = (float)(*loss_acc / (double)red[0]);
}

extern "C" void kernel_launch(void* const* d_in, const int* in_sizes, int n_in,
                              void* d_out, int out_size, void* d_ws, size_t ws_size,
                              hipStream_t stream) {
    const float* hidden = (const float*)d_in[0];  // [2,512,1024] fp32
    const float* W      = (const float*)d_in[1];  // [50000,1024] fp32
    const int*   labels = (const int*)d_in[2];    // [2,512] int
    const float* amask  = (const float*)d_in[3];  // [2,512] fp32
    float* out = (float*)d_out;                   // 51,200,000 logits + 1 loss

    // workspace layout: Wb (bf16, padded) | Ab (bf16) | loss accumulator (double)
    unsigned short* Wb = (unsigned short*)d_ws;
    unsigned short* Ab = Wb + (size_t)NPAD * K_DIM;
    double* loss_acc   = (double*)(Ab + (size_t)M_DIM * K_DIM);

    hipMemsetAsync(loss_acc, 0, sizeof(double), stream);

    convert_all_kernel<<<WCONV_BLOCKS + ACONV_BLOCKS, 256, 0, stream>>>(W, hidden, Wb, Ab);

    dim3 grid(M_DIM / 128, NBLK);  // (8, 391)
    gemm_loss_kernel<<<grid, 256, 0, stream>>>(Ab, Wb, labels, amask, out, loss_acc);

    finalize_kernel<<<1, 256, 0, stream>>>(amask, loss_acc, out + (size_t)M_DIM * V_DIM);
}